// Round 1
// 4374.541 us; speedup vs baseline: 1.2533x; 1.2533x over previous
//
#include <hip/hip_runtime.h>
#include <cmath>

#define Bn   128
#define Cn   8
#define Fn   58
#define Tn   249
#define RCn  24
#define FT   14442      // Fn*Tn
#define CFT  115536     // Cn*Fn*Tn
#define OUTB 346608     // 3*CFT per-batch output
#define IH   60
#define IW   251

// ---------------------------------------------------------------------------
// differ = concat([x[...,:1], W_diff@x + b_diff (shift) - x[...,:-1]], -1)
// Q = wq@differ + bq ; K = wk@differ + bk ; V = differ
// ---------------------------------------------------------------------------
__global__ void k_differ_qk(const float* __restrict__ x,
                            const float* __restrict__ w_diff, const float* __restrict__ b_diff,
                            const float* __restrict__ wq, const float* __restrict__ bq,
                            const float* __restrict__ wk, const float* __restrict__ bk,
                            float* __restrict__ V, float* __restrict__ Q, float* __restrict__ K) {
    int gid = blockIdx.x * blockDim.x + threadIdx.x;
    if (gid >= Bn * FT) return;
    int b  = gid / FT;
    int ft = gid % FT;
    int t  = ft % Tn;
    const float* xb = x + (size_t)b * CFT + ft;

    float xv[Cn], d[Cn];
    #pragma unroll
    for (int c = 0; c < Cn; c++) xv[c] = xb[c * FT];

    if (t == 0) {
        #pragma unroll
        for (int c = 0; c < Cn; c++) d[c] = xv[c];
    } else {
        #pragma unroll
        for (int o = 0; o < Cn; o++) {
            float s = b_diff[o];
            #pragma unroll
            for (int c = 0; c < Cn; c++) s += w_diff[o * Cn + c] * xv[c];
            d[o] = s - xb[o * FT - 1];
        }
    }

    float* Vb = V + (size_t)b * CFT + ft;
    float* Qb = Q + (size_t)b * CFT + ft;
    float* Kb = K + (size_t)b * CFT + ft;
    #pragma unroll
    for (int o = 0; o < Cn; o++) {
        Vb[o * FT] = d[o];
        float q = bq[o], k = bk[o];
        #pragma unroll
        for (int c = 0; c < Cn; c++) { q += wq[o * Cn + c] * d[c]; k += wk[o * Cn + c] * d[c]; }
        Qb[o * FT] = q;
        Kb[o * FT] = k;
    }
}

// ---------------------------------------------------------------------------
// Column-owner register GEMM:
//   out[b, j0+j, l] (+)= sum_m A[b, j0+j, m] * V[b, m, l]   (+ optional bias[j])
// One thread owns one output column l; RG row-accumulators live in VGPRs.
// A^T tile staged once into LDS (rows padded to 16B align; inner-loop reads
// are wave-uniform broadcasts -> conflict-free). V streamed coalesced, each
// column read exactly once per row-group (R0 lesson: the old 16-row x VL tile
// re-streamed V 4x and exposed a scalar global load per FMA burst ->
// VALUBusy 14%).  Flat 1D grid with bijective XCD swizzle so all blocks of a
// batch share one XCD L2 (matters for the N=249 row-grouped case).
// ---------------------------------------------------------------------------
template<int AN, int RG>
__global__ void __launch_bounds__(256)
k_cmm(const float* __restrict__ A, long long aStride,   // per-batch A stride (0 => shared weights)
      const float* __restrict__ bias,                   // nullptr => no bias
      const float* __restrict__ V, long long vStride, int dv,
      float* __restrict__ out, long long oStride, int add,
      int gx, int gy)
{
    constexpr int RGP = (RG + 4) & ~3;   // padded LDS row, 16B-aligned
    __shared__ float As[AN][RGP];

    int nblk = gridDim.x;
    int bid  = blockIdx.x;
    if ((nblk & 7) == 0) {               // bijective XCD swizzle
        int cpx = nblk >> 3;
        bid = (bid & 7) * cpx + (bid >> 3);
    }
    int gxy = gx * gy;
    int b   = bid / gxy;
    int rem = bid - b * gxy;
    int j0  = (rem / gx) * RG;
    int l   = (rem % gx) * 256 + threadIdx.x;

    const float* Ab = A + (size_t)b * aStride;
    for (int idx = threadIdx.x; idx < RG * AN; idx += 256) {
        int j = idx / AN, m = idx - j * AN;
        As[m][j] = (j0 + j < AN) ? Ab[(size_t)(j0 + j) * AN + m] : 0.f;
    }
    __syncthreads();

    if (l >= dv) return;

    float acc[RG];
    #pragma unroll
    for (int j = 0; j < RG; j++) acc[j] = 0.f;

    const float* Vb = V + (size_t)b * vStride + l;
    #pragma unroll 4
    for (int m = 0; m < AN; m++) {
        float v = Vb[(size_t)m * dv];
        #pragma unroll
        for (int j = 0; j < RG; j++) acc[j] += As[m][j] * v;
    }

    float* ob = out + (size_t)b * oStride + l;
    #pragma unroll
    for (int j = 0; j < RG; j++) {
        if (j0 + j < AN) {
            size_t oi = (size_t)(j0 + j) * dv;
            float r = acc[j];
            if (bias) r += bias[j0 + j];
            ob[oi] = add ? ob[oi] + r : r;
        }
    }
}

// ---------------------------------------------------------------------------
// Stride-2 conv variant of the same engine:
//   Y[b, o, l] = bias[o] + sum_i ( W[o,i,0]*X[b,i,2l] + W[o,i,1]*X[b,i,2l+1] )
// ---------------------------------------------------------------------------
template<int AN, int RG>
__global__ void __launch_bounds__(256)
k_cmm_s2(const float* __restrict__ W, const float* __restrict__ bias,
         const float* __restrict__ X, long long xStride, int d_in, int d_out,
         float* __restrict__ out, long long oStride, int gx, int gy)
{
    constexpr int RGP = (RG + 4) & ~3;
    __shared__ float W0s[AN][RGP];
    __shared__ float W1s[AN][RGP];

    int nblk = gridDim.x;
    int bid  = blockIdx.x;
    if ((nblk & 7) == 0) {
        int cpx = nblk >> 3;
        bid = (bid & 7) * cpx + (bid >> 3);
    }
    int gxy = gx * gy;
    int b   = bid / gxy;
    int rem = bid - b * gxy;
    int j0  = (rem / gx) * RG;
    int l   = (rem % gx) * 256 + threadIdx.x;

    for (int idx = threadIdx.x; idx < RG * AN; idx += 256) {
        int j = idx / AN, m = idx - j * AN;
        float w0 = 0.f, w1 = 0.f;
        if (j0 + j < AN) {
            const float* wp = W + ((size_t)(j0 + j) * AN + m) * 2;
            w0 = wp[0]; w1 = wp[1];
        }
        W0s[m][j] = w0;
        W1s[m][j] = w1;
    }
    __syncthreads();

    if (l >= d_out) return;

    float acc[RG];
    #pragma unroll
    for (int j = 0; j < RG; j++) acc[j] = 0.f;

    const float* Xb = X + (size_t)b * xStride + 2 * l;
    #pragma unroll 2
    for (int m = 0; m < AN; m++) {
        float2 xv = *(const float2*)&Xb[(size_t)m * d_in];
        #pragma unroll
        for (int j = 0; j < RG; j++) acc[j] += W0s[m][j] * xv.x + W1s[m][j] * xv.y;
    }

    float* ob = out + (size_t)b * oStride + l;
    #pragma unroll
    for (int j = 0; j < RG; j++) {
        if (j0 + j < AN)
            ob[(size_t)(j0 + j) * d_out] = acc[j] + bias[j0 + j];
    }
}

// ---------------------------------------------------------------------------
// Scores split-K: SP[bz,r,c] = sum_k Q[b,r,k]K[b,c,k]. 64x64 tile, 4x4/thread,
// float4 LDS fragment reads (rows 68 floats = 16B-aligned).
// ---------------------------------------------------------------------------
__global__ void __launch_bounds__(256)
k_scores_sk(const float* __restrict__ Q, const float* __restrict__ K,
            float* __restrict__ SP, int n, int d, int kz_n, int chunk, int sQ) {
    __shared__ float Qs[16][68];
    __shared__ float Ks[16][68];
    int bz = blockIdx.z;
    int b  = bz / kz_n, kz = bz % kz_n;
    int k0 = kz * chunk, k1 = min(d, k0 + chunk);
    int r0 = blockIdx.x * 64, c0 = blockIdx.y * 64;
    int tx = threadIdx.x & 15, ty = threadIdx.x >> 4;
    int lrow = threadIdx.x >> 2;
    int lk   = (threadIdx.x & 3) * 4;
    const float* Qr = Q + (size_t)b * sQ + (size_t)min(r0 + lrow, n - 1) * d;
    const float* Kr = K + (size_t)b * sQ + (size_t)min(c0 + lrow, n - 1) * d;
    bool qok = (r0 + lrow) < n;
    bool kok = (c0 + lrow) < n;
    float acc[4][4] = {};

    for (int kk = k0; kk < k1; kk += 16) {
        #pragma unroll
        for (int u = 0; u < 4; u++) {
            int gk = kk + lk + u;
            bool gv = gk < k1;
            Qs[lk + u][lrow] = (qok && gv) ? Qr[gk] : 0.f;
            Ks[lk + u][lrow] = (kok && gv) ? Kr[gk] : 0.f;
        }
        __syncthreads();
        #pragma unroll
        for (int k = 0; k < 16; k++) {
            float4 q4 = *(const float4*)&Qs[k][ty * 4];
            float4 k4 = *(const float4*)&Ks[k][tx * 4];
            float aq[4] = {q4.x, q4.y, q4.z, q4.w};
            float ak[4] = {k4.x, k4.y, k4.z, k4.w};
            #pragma unroll
            for (int i = 0; i < 4; i++)
                #pragma unroll
                for (int j = 0; j < 4; j++) acc[i][j] += aq[i] * ak[j];
        }
        __syncthreads();
    }
    float* Sb = SP + (size_t)bz * n * n;
    #pragma unroll
    for (int i = 0; i < 4; i++) {
        int r = r0 + ty * 4 + i;
        #pragma unroll
        for (int j = 0; j < 4; j++) {
            int c = c0 + tx * 4 + j;
            if (r < n && c < n) Sb[(size_t)r * n + c] = acc[i][j];
        }
    }
}

// ---------------------------------------------------------------------------
// Combine split-K partials (no scale — softmax folds 1/sqrt(d)).
// ---------------------------------------------------------------------------
__global__ void k_scombine(const float* __restrict__ SP, float* __restrict__ S,
                           int n, int kz_n) {
    int idx = blockIdx.x * 256 + threadIdx.x;
    int nn = n * n;
    if (idx >= Bn * nn) return;
    int b = idx / nn, rc = idx % nn;
    float s = 0.f;
    for (int kz = 0; kz < kz_n; kz++) s += SP[((size_t)b * kz_n + kz) * nn + rc];
    S[(size_t)b * nn + rc] = s;
}

// ---------------------------------------------------------------------------
// c-branch gram: 8x8 over d=FT, 8 l-chunks of partials.
// ---------------------------------------------------------------------------
#define C_LZ 8
__global__ void k_gram8(const float* __restrict__ Q, const float* __restrict__ K,
                        float* __restrict__ SP) {
    int b  = blockIdx.x / C_LZ;
    int lz = blockIdx.x % C_LZ;
    int g  = threadIdx.x >> 6;
    int p  = threadIdx.x & 63;
    int r  = p >> 3, c = p & 7;
    const float* Qb = Q + (size_t)b * CFT + (size_t)r * FT;
    const float* Kb = K + (size_t)b * CFT + (size_t)c * FT;
    int chunk = (FT + C_LZ - 1) / C_LZ;
    int l0 = lz * chunk, l1 = min(FT, l0 + chunk);
    float acc = 0.f;
    for (int l = l0 + g; l < l1; l += 4) acc += Qb[l] * Kb[l];
    __shared__ float red[256];
    red[threadIdx.x] = acc;
    __syncthreads();
    if (threadIdx.x < 64) {
        float s = red[p] + red[64 + p] + red[128 + p] + red[192 + p];
        SP[(size_t)blockIdx.x * 64 + p] = s;
    }
}

// ---------------------------------------------------------------------------
// column softmax in-place (axis=1), folds the 1/sqrt(d) scale.
// ---------------------------------------------------------------------------
__global__ void k_softmax(float* __restrict__ S, int n, int mb, float scale) {
    int b = blockIdx.x / mb;
    int m = (blockIdx.x % mb) * 64 + threadIdx.x;
    if (m >= n) return;
    float* Sb = S + (size_t)b * n * n;
    float mx = -1e30f;
    for (int r = 0; r < n; r++) mx = fmaxf(mx, Sb[(size_t)r * n + m]);
    float sum = 0.f;
    for (int r = 0; r < n; r++) {
        float e = __expf((Sb[(size_t)r * n + m] - mx) * scale);
        Sb[(size_t)r * n + m] = e;
        sum += e;
    }
    float inv = 1.f / sum;
    for (int r = 0; r < n; r++) Sb[(size_t)r * n + m] *= inv;
}

// ---------------------------------------------------------------------------
// xr spatial mean per (b, rc)
// ---------------------------------------------------------------------------
__global__ void k_mean(const float* __restrict__ inp, const float* __restrict__ w_res,
                       const float* __restrict__ b_res, const float* __restrict__ bn_gamma,
                       const float* __restrict__ bn_beta, const float* __restrict__ bn_mean,
                       const float* __restrict__ bn_var, float* __restrict__ meanbuf) {
    int b  = blockIdx.x / RCn;
    int rc = blockIdx.x % RCn;
    float w[9];
    #pragma unroll
    for (int i = 0; i < 9; i++) w[i] = w_res[rc * 9 + i];
    float g    = bn_gamma[rc] * rsqrtf(bn_var[rc] + 1e-5f);
    float bias = (b_res[rc] - bn_mean[rc]) * g + bn_beta[rc];
    const float* ib = inp + (size_t)b * IH * IW;

    float sum = 0.f;
    for (int idx = threadIdx.x; idx < FT; idx += 256) {
        int f = idx / Tn, t = idx % Tn;
        const float* p = ib + f * IW + t;
        float v = w[0]*p[0]     + w[1]*p[1]     + w[2]*p[2]
                + w[3]*p[IW]    + w[4]*p[IW+1]  + w[5]*p[IW+2]
                + w[6]*p[2*IW]  + w[7]*p[2*IW+1]+ w[8]*p[2*IW+2];
        sum += v * g + bias;
    }
    __shared__ float red[256];
    red[threadIdx.x] = sum;
    __syncthreads();
    for (int s = 128; s > 0; s >>= 1) {
        if (threadIdx.x < s) red[threadIdx.x] += red[threadIdx.x + s];
        __syncthreads();
    }
    if (threadIdx.x == 0) meanbuf[b * RCn + rc] = red[0] / (float)FT;
}

// ---------------------------------------------------------------------------
// dyReLU coefficient MLP
// ---------------------------------------------------------------------------
__global__ void k_coef(const float* __restrict__ meanbuf, const float* __restrict__ w1,
                       const float* __restrict__ b1, const float* __restrict__ w2,
                       const float* __restrict__ b2, float* __restrict__ coef) {
    int b = blockIdx.x;
    int k = threadIdx.x;
    if (k >= 4 * RCn) return;
    const float* th = meanbuf + b * RCn;
    float h[6];
    #pragma unroll
    for (int j = 0; j < 6; j++) {
        float s = b1[j];
        #pragma unroll
        for (int c = 0; c < RCn; c++) s += th[c] * w1[j * RCn + c];
        h[j] = fmaxf(s, 0.f);
    }
    float s = b2[k];
    #pragma unroll
    for (int j = 0; j < 6; j++) s += h[j] * w2[k * 6 + j];
    float g2 = 2.f / (1.f + __expf(-s)) - 1.f;
    const float lam[4] = {1.f, 1.f, 0.5f, 0.5f};
    const float ini[4] = {1.f, 0.f, 0.f, 0.f};
    coef[b * 96 + k] = g2 * lam[k & 3] + ini[k & 3];
}

// ---------------------------------------------------------------------------
// recompute conv+BN, apply dyReLU, out += xr
// ---------------------------------------------------------------------------
__global__ void k_xr_add(const float* __restrict__ inp, const float* __restrict__ w_res,
                         const float* __restrict__ b_res, const float* __restrict__ bn_gamma,
                         const float* __restrict__ bn_beta, const float* __restrict__ bn_mean,
                         const float* __restrict__ bn_var, const float* __restrict__ coef,
                         float* __restrict__ out) {
    int gid = blockIdx.x * blockDim.x + threadIdx.x;
    if (gid >= Bn * RCn * FT) return;
    int t   = gid % Tn;
    int tmp = gid / Tn;
    int f   = tmp % Fn;  tmp /= Fn;
    int rc  = tmp % RCn;
    int b   = tmp / RCn;

    const float* wp = w_res + rc * 9;
    float g    = bn_gamma[rc] * rsqrtf(bn_var[rc] + 1e-5f);
    float bias = (b_res[rc] - bn_mean[rc]) * g + bn_beta[rc];
    const float* p = inp + (size_t)b * IH * IW + f * IW + t;
    float v = wp[0]*p[0]    + wp[1]*p[1]      + wp[2]*p[2]
            + wp[3]*p[IW]   + wp[4]*p[IW+1]   + wp[5]*p[IW+2]
            + wp[6]*p[2*IW] + wp[7]*p[2*IW+1] + wp[8]*p[2*IW+2];
    float xv = v * g + bias;

    const float* cf = coef + ((size_t)b * RCn + rc) * 4;
    float r = fmaxf(xv * cf[0] + cf[2], xv * cf[1] + cf[3]);
    out[gid] += r;
}

// ---------------------------------------------------------------------------
extern "C" void kernel_launch(void* const* d_in, const int* in_sizes, int n_in,
                              void* d_out, int out_size, void* d_ws, size_t ws_size,
                              hipStream_t stream) {
    const float* x        = (const float*)d_in[0];
    const float* inp      = (const float*)d_in[1];
    const float* w_diff   = (const float*)d_in[2];
    const float* b_diff   = (const float*)d_in[3];
    const float* w_res    = (const float*)d_in[4];
    const float* b_res    = (const float*)d_in[5];
    const float* bn_gamma = (const float*)d_in[6];
    const float* bn_beta  = (const float*)d_in[7];
    const float* bn_mean  = (const float*)d_in[8];
    const float* bn_var   = (const float*)d_in[9];
    const float* dy_w1    = (const float*)d_in[10];
    const float* dy_b1    = (const float*)d_in[11];
    const float* dy_w2    = (const float*)d_in[12];
    const float* dy_b2    = (const float*)d_in[13];
    const float* wq       = (const float*)d_in[14];
    const float* bq       = (const float*)d_in[15];
    const float* wk       = (const float*)d_in[16];
    const float* bk       = (const float*)d_in[17];
    const float* fq0_w    = (const float*)d_in[18];
    const float* fq0_b    = (const float*)d_in[19];
    const float* fk0_w    = (const float*)d_in[20];
    const float* fk0_b    = (const float*)d_in[21];
    const float* cq0_w    = (const float*)d_in[22];
    const float* cq0_b    = (const float*)d_in[23];
    const float* ck0_w    = (const float*)d_in[24];
    const float* ck0_b    = (const float*)d_in[25];
    const float* tq0_w    = (const float*)d_in[26];
    const float* tq0_b    = (const float*)d_in[27];
    const float* tk0_w    = (const float*)d_in[28];
    const float* tk0_b    = (const float*)d_in[29];
    const float* tq1_w    = (const float*)d_in[30];
    const float* tq1_b    = (const float*)d_in[31];
    const float* tk1_w    = (const float*)d_in[32];
    const float* tk1_b    = (const float*)d_in[33];

    float* out = (float*)d_out;
    float* ws  = (float*)d_ws;

    const size_t NB = (size_t)Bn * CFT;
    float* V       = ws;
    float* Q       = ws + NB;
    float* K       = ws + 2 * NB;
    float* Qp      = ws + 3 * NB;
    float* Kp      = ws + 4 * NB;
    float* S       = ws + 5 * NB;                       // up to Bn*Tn*Tn floats
    float* SP      = S + 4200000;                        // split-K partials
    float* meanbuf = S + (size_t)Bn * Tn * Tn;
    float* coef    = meanbuf + Bn * RCn;

    {
        int total = Bn * FT;
        k_differ_qk<<<dim3((total + 255) / 256), dim3(256), 0, stream>>>(
            x, w_diff, b_diff, wq, bq, wk, bk, V, Q, K);
    }

    // scores + softmax for the f / t branches (unchanged engines)
    auto attend_nt = [&](const float* Qv, const float* Kv, int n, int dq, int sQ,
                         int KZ, int sec, int add) {
        float scale = 1.0f / sqrtf((float)dq);
        int chunk = ((dq + KZ * 32 - 1) / (KZ * 32)) * 32;
        float* SPb = (KZ == 1) ? S : SP;
        dim3 g1((n + 63) / 64, (n + 63) / 64, Bn * KZ);
        k_scores_sk<<<g1, dim3(256), 0, stream>>>(Qv, Kv, SPb, n, dq, KZ, chunk, sQ);
        if (KZ > 1) {
            int nn = n * n;
            k_scombine<<<dim3((Bn * nn + 255) / 256), dim3(256), 0, stream>>>(SPb, S, n, KZ);
        }
        int mb = (n + 63) / 64;
        k_softmax<<<dim3(Bn * mb), dim3(64), 0, stream>>>(S, n, mb, scale);
        // apply: out[sec] (+)= S @ V  via column-owner GEMM
        if (n == Fn) {
            // dv=1992, gx=8 cols-blocks, gy=1 (all 58 rows in registers)
            k_cmm<Fn, Fn><<<dim3(Bn * 8), dim3(256), 0, stream>>>(
                S, (long long)Fn * Fn, nullptr, V, CFT, 1992,
                out + (size_t)sec * CFT, OUTB, add, 8, 1);
        } else {
            // n=249: dv=464, gx=2, gy=4 row-groups of 64
            k_cmm<Tn, 64><<<dim3(Bn * 8), dim3(256), 0, stream>>>(
                S, (long long)Tn * Tn, nullptr, V, CFT, 464,
                out + (size_t)sec * CFT, OUTB, add, 2, 4);
        }
    };

    auto attend_c = [&](const float* Qv, const float* Kv, int add) {
        k_gram8<<<dim3(Bn * C_LZ), dim3(256), 0, stream>>>(Qv, Kv, SP);
        k_scombine<<<dim3((Bn * 64 + 255) / 256), dim3(256), 0, stream>>>(SP, S, Cn, C_LZ);
        k_softmax<<<dim3(Bn), dim3(64), 0, stream>>>(S, Cn, 1, 1.0f / sqrtf((float)FT));
        // dv=14442 -> gx=57
        k_cmm<Cn, Cn><<<dim3(Bn * 57), dim3(256), 0, stream>>>(
            S, (long long)Cn * Cn, nullptr, V, CFT, FT, out + CFT, OUTB, add, 57, 1);
    };

    // ---- f branch: n=58, d=1992, sec=0, split-K 8
    attend_nt(Q, K, Fn, 1992, CFT, 8, 0, 0);
    k_cmm<Fn, Fn><<<dim3(Bn * 8), dim3(256), 0, stream>>>(
        fq0_w, 0, fq0_b, Q, CFT, 1992, Qp, CFT, 0, 8, 1);
    k_cmm<Fn, Fn><<<dim3(Bn * 8), dim3(256), 0, stream>>>(
        fk0_w, 0, fk0_b, K, CFT, 1992, Kp, CFT, 0, 8, 1);
    attend_nt(Qp, Kp, Fn, 1992, CFT, 8, 0, 1);

    // ---- c branch: n=8, d=14442, sec=1
    attend_c(Q, K, 0);
    k_cmm<Cn, Cn><<<dim3(Bn * 57), dim3(256), 0, stream>>>(
        cq0_w, 0, cq0_b, Q, CFT, FT, Qp, CFT, 0, 57, 1);
    k_cmm<Cn, Cn><<<dim3(Bn * 57), dim3(256), 0, stream>>>(
        ck0_w, 0, ck0_b, K, CFT, FT, Kp, CFT, 0, 57, 1);
    attend_c(Qp, Kp, 1);

    // ---- t branch: n=249, dv=464, sec=2
    attend_nt(Q, K, Tn, 464, CFT, 1, 2, 0);
    k_cmm<Tn, 64><<<dim3(Bn * 8), dim3(256), 0, stream>>>(
        tq0_w, 0, tq0_b, Q, CFT, 464, Qp, CFT, 0, 2, 4);
    k_cmm<Tn, 64><<<dim3(Bn * 8), dim3(256), 0, stream>>>(
        tk0_w, 0, tk0_b, K, CFT, 464, Kp, CFT, 0, 2, 4);
    attend_nt(Qp, Kp, Tn, 464, CFT, 1, 2, 1);
    // stride-2 conv: d_out=232 -> gx=1, gy=8 row-groups of 32
    k_cmm_s2<Tn, 32><<<dim3(Bn * 8), dim3(256), 0, stream>>>(
        tq1_w, tq1_b, Q, CFT, 464, 232, Qp, (long long)Tn * 232, 1, 8);
    k_cmm_s2<Tn, 32><<<dim3(Bn * 8), dim3(256), 0, stream>>>(
        tk1_w, tk1_b, K, CFT, 464, 232, Kp, (long long)Tn * 232, 1, 8);
    attend_nt(Qp, Kp, Tn, 232, Tn * 232, 1, 2, 1);

    // ---- xr residual path
    k_mean<<<dim3(Bn * RCn), dim3(256), 0, stream>>>(
        inp, w_res, b_res, bn_gamma, bn_beta, bn_mean, bn_var, meanbuf);
    k_coef<<<dim3(Bn), dim3(128), 0, stream>>>(meanbuf, dy_w1, dy_b1, dy_w2, dy_b2, coef);
    {
        int total = Bn * RCn * FT;
        k_xr_add<<<dim3((total + 255) / 256), dim3(256), 0, stream>>>(
            inp, w_res, b_res, bn_gamma, bn_beta, bn_mean, bn_var, coef, out);
    }
}